// Round 5
// baseline (498.259 us; speedup 1.0000x reference)
//
#include <hip/hip_runtime.h>
#include <math.h>

#define B_ 32
#define L_ 512
#define H_ 336
#define C_ 321
#define K_ 8
#define S_ 8
#define FREQ_ 169   // H/2+1
#define G_ 17       // 2K+1
#define LH_ 848     // L+H
#define F_FEAT 520  // L+K
#define EPS_ 1e-5f
#define BCN_ (B_ * C_)   // 10272
#define BCB_ 7           // bc per k_dftz block (63 of 64 M-rows used)

#ifndef M_PIf
#define M_PIf 3.14159265358979323846f
#endif

typedef __attribute__((ext_vector_type(8))) short short8v;
typedef __attribute__((ext_vector_type(4))) float f32x4;

__device__ __forceinline__ unsigned short f2bf(float x) {
    unsigned u = __builtin_bit_cast(unsigned, x);
    u += 0x7FFFu + ((u >> 16) & 1u);
    return (unsigned short)(u >> 16);
}
__device__ __forceinline__ float bf2f(unsigned short h) {
    return __builtin_bit_cast(float, (unsigned)h << 16);
}

// ================= prep kernels: build MFMA-fragment-swizzled B matrices ==========
// Fragment layout (16x16x32 bf16): b-frag lane l holds B[kc*32 + (l>>4)*8 + i][nt*16 + (l&15)].
// Stored flat: elem((kc*NT + nt)*512 + l*8 + i).

// DFT table: K=352 (336 used), N=352 (338 used). col 2f=cos(2pi k f/H), 2f+1=-sin.
__global__ void k_prep_dft(unsigned short* __restrict__ T) {   // grid 11*22, 64 thr
    int blk = blockIdx.x, kc = blk / 22, nt = blk % 22, lane = threadIdx.x;
    int n = nt * 16 + (lane & 15);
    int kb = kc * 32 + (lane >> 4) * 8;
    int f = n >> 1;
    unsigned short* dst = T + (size_t)blk * 512 + lane * 8;
    for (int i = 0; i < 8; ++i) {
        int k = kb + i;
        float val = 0.f;
        if (k < H_ && n < 2 * FREQ_) {
            int m = (k * f) % H_;
            float s, c;
            sincosf((float)m * (2.0f * M_PIf / (float)H_), &s, &c);
            val = (n & 1) ? -s : c;
        }
        dst[i] = f2bf(val);
    }
}

// irfft table: K=352 (338 used; row 2f = cos, 2f+1 = -sin), N=336.
__global__ void k_prep_ir(unsigned short* __restrict__ T) {    // grid 11*21, 64 thr
    int blk = blockIdx.x, kc = blk / 21, nt = blk % 21, lane = threadIdx.x;
    int h = nt * 16 + (lane & 15);
    int kb = kc * 32 + (lane >> 4) * 8;
    unsigned short* dst = T + (size_t)blk * 512 + lane * 8;
    for (int i = 0; i < 8; ++i) {
        int k = kb + i;
        float val = 0.f;
        if (k < 2 * FREQ_) {
            int f = k >> 1;
            int m = (f * h) % H_;
            float s, c;
            sincosf((float)m * (2.0f * M_PIf / (float)H_), &s, &c);
            val = (k & 1) ? -s : c;
        }
        dst[i] = f2bf(val);
    }
}

// Mixing matrix: K=1024 (rows 0..506 = zr, 512..1018 = zi), N=352 (338 used).
__global__ void k_prep_w2(const float* __restrict__ Wm_re, const float* __restrict__ Wm_im,
                          unsigned short* __restrict__ T) {    // grid 32*22, 64 thr
    int blk = blockIdx.x, kc = blk / 22, nt = blk % 22, lane = threadIdx.x;
    int n = nt * 16 + (lane & 15);
    int kb = kc * 32 + (lane >> 4) * 8;
    int g = n >> 1;
    unsigned short* dst = T + (size_t)blk * 512 + lane * 8;
    for (int i = 0; i < 8; ++i) {
        int k = kb + i;
        float val = 0.f;
        if (n < 2 * FREQ_) {
            if (k < 3 * FREQ_) {
                int j = k;
                val = (n & 1) ? Wm_im[(size_t)g * (3 * FREQ_) + j]
                              : Wm_re[(size_t)g * (3 * FREQ_) + j];
            } else if (k >= 512 && k < 512 + 3 * FREQ_) {
                int j = k - 512;
                val = (n & 1) ? Wm_re[(size_t)g * (3 * FREQ_) + j]
                              : -Wm_im[(size_t)g * (3 * FREQ_) + j];
            }
        }
        dst[i] = f2bf(val);
    }
}

// Wb for y_hat GEMM: B[k][n] = Wb[n][k]. K=512, N=336.
__global__ void k_prep_wb(const float* __restrict__ Wb, unsigned short* __restrict__ T) { // grid 16*21, 64 thr
    int blk = blockIdx.x, kc = blk / 21, nt = blk % 21, lane = threadIdx.x;
    int n = nt * 16 + (lane & 15);
    int kb = kc * 32 + (lane >> 4) * 8;
    unsigned short* dst = T + (size_t)blk * 512 + lane * 8;
    for (int i = 0; i < 8; ++i) {
        int k = kb + i;
        dst[i] = f2bf(Wb[(size_t)n * L_ + k]);
    }
}

// states repack, f-major for the combine phase:
// stf4[(k*8+s)*169 + f] = {st[s][k][f].re, st[s][k][f].im, st[s][8+k][f].re, st[s][8+k][f].im}
// stg3[s*169 + f]       = {st[s][16][f].re, st[s][16][f].im}
__global__ __launch_bounds__(256) void k_prep_st2(const float* __restrict__ st_re,
                                                  const float* __restrict__ st_im,
                                                  float4* __restrict__ stf4,
                                                  float2* __restrict__ stg3) {
    int idx = blockIdx.x * 256 + threadIdx.x;
    if (idx < 64 * FREQ_) {
        int row = idx / FREQ_, f = idx % FREQ_;
        int k = row >> 3, s = row & 7;
        size_t b1 = (size_t)s * (G_ * FREQ_) + (size_t)k * FREQ_ + f;
        size_t b2 = (size_t)s * (G_ * FREQ_) + (size_t)(8 + k) * FREQ_ + f;
        stf4[idx] = make_float4(st_re[b1], st_im[b1], st_re[b2], st_im[b2]);
    }
    if (idx < 8 * FREQ_) {
        int s = idx / FREQ_, f = idx % FREQ_;
        size_t b3 = (size_t)s * (G_ * FREQ_) + (size_t)16 * FREQ_ + f;
        stg3[idx] = make_float2(st_re[b3], st_im[b3]);
    }
}

// ================= K1: LayerNorm, coalesced + LDS transpose =================
__global__ __launch_bounds__(256) void k_ln2(const float* __restrict__ x,
                                             float* __restrict__ full,
                                             unsigned short* __restrict__ xnbf,
                                             float* __restrict__ muv,
                                             float* __restrict__ nrm) {
    __shared__ float tl[64][65];
    __shared__ float red_s[4][64], red_q[4][64];
    __shared__ float sMu[64], sInv[64];
    int tid = threadIdx.x, w = tid >> 6, lane = tid & 63;
    int b = blockIdx.y, c0 = blockIdx.x * 64;
    int c = c0 + lane;
    bool valid = (c < C_);
    const float* xb = x + ((size_t)b * L_) * C_;

    float s = 0.f, q = 0.f;
    for (int l = w; l < L_; l += 4) {
        float v = valid ? xb[(size_t)l * C_ + c] : 0.f;
        s += v; q += v * v;
    }
    red_s[w][lane] = s; red_q[w][lane] = q;
    __syncthreads();
    if (w == 0) {
        float S = red_s[0][lane] + red_s[1][lane] + red_s[2][lane] + red_s[3][lane];
        float Q = red_q[0][lane] + red_q[1][lane] + red_q[2][lane] + red_q[3][lane];
        float mu = S / (float)L_;
        float var = Q / (float)L_ - mu * mu;
        float n = sqrtf(var + EPS_);
        sMu[lane] = mu; sInv[lane] = 1.0f / n;
        if (valid) { muv[(size_t)b * C_ + c] = mu; nrm[(size_t)b * C_ + c] = n; }
    }
    __syncthreads();
    float mu = sMu[lane], inv = sInv[lane];

    for (int l0 = 0; l0 < L_; l0 += 64) {
        for (int li = w; li < 64; li += 4) {
            float v = valid ? xb[(size_t)(l0 + li) * C_ + c] : 0.f;
            tl[li][lane] = (v - mu) * inv;
        }
        __syncthreads();
        for (int cr = w; cr < 64; cr += 4) {
            int cc = c0 + cr;
            if (cc < C_) {
                size_t bc = (size_t)b * C_ + cc;
                full[bc * LH_ + l0 + lane] = tl[lane][cr];
                if (lane < 32) {
                    unsigned pk = (unsigned)f2bf(tl[2 * lane][cr]) |
                                  ((unsigned)f2bf(tl[2 * lane + 1][cr]) << 16);
                    ((unsigned*)xnbf)[bc * 256 + l0 / 2 + lane] = pk;
                }
            }
        }
        __syncthreads();
    }
}

// ================= K2: y_hat via MFMA: full[:,512:848] = xn @ Wb^T + bb ======
__global__ __launch_bounds__(256) void k_yhat(const unsigned short* __restrict__ xnbf,
                                              const unsigned short* __restrict__ Wbsw,
                                              const float* __restrict__ bb,
                                              float* __restrict__ full) {
    int bc0 = blockIdx.x * 32;
    int tid = threadIdx.x, w = tid >> 6, lane = tid & 63;
    const int NTB[5] = {0, 6, 11, 16, 21};
    int nt0 = NTB[w], ntn = NTB[w + 1] - nt0;
    int r15 = lane & 15, kg = lane >> 4;
    f32x4 acc[2][6];
    #pragma unroll
    for (int mf = 0; mf < 2; ++mf)
        #pragma unroll
        for (int j = 0; j < 6; ++j) acc[mf][j] = (f32x4){0.f, 0.f, 0.f, 0.f};
    for (int kc = 0; kc < 16; ++kc) {
        short8v a[2];
        #pragma unroll
        for (int mf = 0; mf < 2; ++mf)
            a[mf] = *(const short8v*)(xnbf + ((size_t)(bc0 + mf * 16 + r15) * L_ + kc * 32 + kg * 8));
        #pragma unroll
        for (int j = 0; j < 6; ++j) {
            if (j >= ntn) continue;
            short8v bfr = *(const short8v*)(Wbsw + ((size_t)(kc * 21 + nt0 + j) * 512 + lane * 8));
            #pragma unroll
            for (int mf = 0; mf < 2; ++mf)
                acc[mf][j] = __builtin_amdgcn_mfma_f32_16x16x32_bf16(a[mf], bfr, acc[mf][j], 0, 0, 0);
        }
    }
    #pragma unroll
    for (int mf = 0; mf < 2; ++mf)
        #pragma unroll
        for (int j = 0; j < 6; ++j) {
            if (j >= ntn) continue;
            int n_ = (nt0 + j) * 16 + r15;
            #pragma unroll
            for (int reg = 0; reg < 4; ++reg) {
                int bc = bc0 + mf * 16 + kg * 4 + reg;
                full[(size_t)bc * LH_ + L_ + n_] = acc[mf][j][reg] + bb[n_];
            }
        }
}

// ================= K3: r_soft + feat @ Wc^T + softmax -> p (Wc in LDS) =======
// Block = 16 bc (4 waves x 4 bc each). grid = BCN_/16 = 642.
__global__ __launch_bounds__(256) void k_p2(const float* __restrict__ full,
                                            const float* __restrict__ r,
                                            const float* __restrict__ Wc,
                                            const float* __restrict__ bcv,
                                            float* __restrict__ p_out) {
    __shared__ float WcS[8 * F_FEAT];
    __shared__ float rsS[16][8];
    __shared__ float bcS[8];
    int tid = threadIdx.x, w = tid >> 6, lane = tid & 63;
    int bc0 = blockIdx.x * 16;
    for (int i = tid; i < 8 * F_FEAT; i += 256) WcS[i] = Wc[i];
    if (tid < 8) bcS[tid] = bcv[tid];
    if (tid < 16) {
        int bc = bc0 + tid;
        const float* rr = r + (size_t)bc * K_;
        float a[8]; float m = 1.0f;
        #pragma unroll
        for (int k = 0; k < 8; ++k) { a[k] = fabsf(rr[k]); m = fmaxf(m, a[k]); }
        float Z = expf(1.0f - m);
        float e[8];
        #pragma unroll
        for (int k = 0; k < 8; ++k) { e[k] = expf(a[k] - m); Z += e[k]; }
        float inv = 1.0f / Z;
        #pragma unroll
        for (int k = 0; k < 8; ++k) rsS[tid][k] = e[k] * inv;
    }
    __syncthreads();

    for (int i = 0; i < 4; ++i) {
        int bcl = w * 4 + i;
        int bc = bc0 + bcl;
        const float* xrow = full + (size_t)bc * LH_;
        float acc[8] = {0.f, 0.f, 0.f, 0.f, 0.f, 0.f, 0.f, 0.f};
        #pragma unroll
        for (int t = 0; t < 8; ++t) {
            int f = lane + t * 64;
            float xf = xrow[f];
            #pragma unroll
            for (int s = 0; s < 8; ++s) acc[s] += xf * WcS[s * F_FEAT + f];
        }
        if (lane < 8) {
            float xf = rsS[bcl][lane];
            #pragma unroll
            for (int s = 0; s < 8; ++s) acc[s] += xf * WcS[s * F_FEAT + L_ + lane];
        }
        #pragma unroll
        for (int s = 0; s < 8; ++s) {
            #pragma unroll
            for (int off = 32; off > 0; off >>= 1) acc[s] += __shfl_down(acc[s], off);
        }
        if (lane == 0) {
            float m = -1e30f;
            #pragma unroll
            for (int s = 0; s < 8; ++s) { acc[s] += bcS[s]; m = fmaxf(m, acc[s]); }
            float Z = 0.f; float e[8];
            #pragma unroll
            for (int s = 0; s < 8; ++s) { e[s] = expf(acc[s] - m); Z += e[s]; }
            float inv = 1.0f / Z;
            #pragma unroll
            for (int s = 0; s < 8; ++s) p_out[(size_t)bc * 8 + s] = e[s] * inv;
        }
    }
}

// ================= K4: fused DFT (MFMA) + filter-combine -> z ================
__global__ __launch_bounds__(256) void k_dftz(const float* __restrict__ full,
                                              const int* __restrict__ leader,
                                              const int* __restrict__ shiftp,
                                              const unsigned short* __restrict__ Tsw,
                                              const float* __restrict__ pbuf,
                                              const float4* __restrict__ stf4,
                                              const float2* __restrict__ stg3,
                                              unsigned short* __restrict__ zbf) {
    __shared__ unsigned short A[64 * 360];
    __shared__ float psL[BCB_][8];
    int tid = threadIdx.x, w = tid >> 6, lane = tid & 63;
    int bc0 = blockIdx.x * BCB_;
    unsigned* A32 = (unsigned*)A;
    for (int i = tid; i < 64 * 180; i += 256) A32[i] = 0;
    if (tid < BCB_ * 8) {
        int bcl = tid >> 3, s = tid & 7;
        int bc = bc0 + bcl;
        psL[bcl][s] = (bc < BCN_) ? pbuf[(size_t)bc * 8 + s] : 0.f;
    }
    __syncthreads();

    // gather 63 rows (row = bcl*9 + k)
    for (int rr = w; rr < 63; rr += 4) {
        int bcl = rr / 9, k = rr - bcl * 9;
        int bc = bc0 + bcl;
        if (bc < BCN_) {
            int b = bc / C_;
            const float* src;
            if (k < 8) {
                int lead = leader[(size_t)bc * K_ + k];
                int sh = shiftp[(size_t)bc * K_ + k];
                src = full + ((size_t)b * C_ + lead) * LH_ + (L_ - sh);
            } else {
                src = full + (size_t)bc * LH_ + L_;
            }
            unsigned* dst = A32 + rr * 180;
            for (int j = lane; j < 168; j += 64) {
                float2 v = *(const float2*)(src + 2 * j);
                dst[j] = (unsigned)f2bf(v.x) | ((unsigned)f2bf(v.y) << 16);
            }
        }
    }
    __syncthreads();

    // MFMA: 4 M-frags x (<=6) N-frags x 11 K-tiles
    const int NTB[5] = {0, 6, 12, 17, 22};
    int nt0 = NTB[w], ntn = NTB[w + 1] - nt0;
    int r15 = lane & 15, kg = lane >> 4;
    f32x4 acc[4][6];
    #pragma unroll
    for (int mf = 0; mf < 4; ++mf)
        #pragma unroll
        for (int j = 0; j < 6; ++j) acc[mf][j] = (f32x4){0.f, 0.f, 0.f, 0.f};
    for (int kc = 0; kc < 11; ++kc) {
        short8v a[4];
        #pragma unroll
        for (int mf = 0; mf < 4; ++mf)
            a[mf] = *(const short8v*)(A + (size_t)(mf * 16 + r15) * 360 + kc * 32 + kg * 8);
        #pragma unroll
        for (int j = 0; j < 6; ++j) {
            if (j >= ntn) continue;
            short8v bfr = *(const short8v*)(Tsw + ((size_t)(kc * 22 + nt0 + j) * 512 + lane * 8));
            #pragma unroll
            for (int mf = 0; mf < 4; ++mf)
                acc[mf][j] = __builtin_amdgcn_mfma_f32_16x16x32_bf16(a[mf], bfr, acc[mf][j], 0, 0, 0);
        }
    }
    __syncthreads();   // A dead; safe to overwrite with X

    // store X (bf16) into LDS
    #pragma unroll
    for (int mf = 0; mf < 4; ++mf)
        #pragma unroll
        for (int j = 0; j < 6; ++j) {
            if (j >= ntn) continue;
            int col = (nt0 + j) * 16 + r15;
            #pragma unroll
            for (int reg = 0; reg < 4; ++reg) {
                int row = mf * 16 + kg * 4 + reg;
                A[row * 360 + col] = f2bf(acc[mf][j][reg]);
            }
        }
    __syncthreads();

    // combine -> z : thread = f, loop k outer, reuse state loads across all 7 bc
    if (tid < FREQ_) {
        int f = tid;
        float z1r[BCB_], z1i[BCB_], z2r[BCB_], z2i[BCB_], Yr[BCB_], Yi[BCB_];
        #pragma unroll
        for (int bcl = 0; bcl < BCB_; ++bcl) {
            z1r[bcl] = z1i[bcl] = z2r[bcl] = z2i[bcl] = 0.f;
            unsigned v = A32[(bcl * 9 + 8) * 180 + f];
            Yr[bcl] = bf2f((unsigned short)(v & 0xffff));
            Yi[bcl] = bf2f((unsigned short)(v >> 16));
        }
        for (int k = 0; k < 8; ++k) {
            float4 stv[8];
            #pragma unroll
            for (int s = 0; s < 8; ++s) stv[s] = stf4[(size_t)(k * 8 + s) * FREQ_ + f];
            #pragma unroll
            for (int bcl = 0; bcl < BCB_; ++bcl) {
                float f1r = 0.f, f1i = 0.f, f2r = 0.f, f2i = 0.f;
                #pragma unroll
                for (int s = 0; s < 8; ++s) {
                    float p = psL[bcl][s];
                    f1r += p * stv[s].x; f1i += p * stv[s].y;
                    f2r += p * stv[s].z; f2i += p * stv[s].w;
                }
                unsigned v = A32[(bcl * 9 + k) * 180 + f];
                float Xr = bf2f((unsigned short)(v & 0xffff));
                float Xi = bf2f((unsigned short)(v >> 16));
                float ar = Xr * f1r - Xi * f1i;
                float ai = Xr * f1i + Xi * f1r;
                z1r[bcl] += ar; z1i[bcl] += ai;
                float dr = ar - Yr[bcl], di = ai - Yi[bcl];
                z2r[bcl] += dr * f2r - di * f2i;
                z2i[bcl] += dr * f2i + di * f2r;
            }
        }
        #pragma unroll
        for (int bcl = 0; bcl < BCB_; ++bcl) {
            int bc = bc0 + bcl;
            if (bc >= BCN_) continue;
            float f3r = 0.f, f3i = 0.f;
            #pragma unroll
            for (int s = 0; s < 8; ++s) {
                float2 v3 = stg3[(size_t)s * FREQ_ + f];
                float p = psL[bcl][s];
                f3r += p * v3.x; f3i += p * v3.y;
            }
            unsigned short* zrow = zbf + (size_t)bc * 1024;
            zrow[f]       = f2bf(z1r[bcl]);  zrow[512 + f]       = f2bf(z1i[bcl]);
            zrow[169 + f] = f2bf(z2r[bcl]);  zrow[512 + 169 + f] = f2bf(z2i[bcl]);
            zrow[338 + f] = f2bf(Yr[bcl] * f3r - Yi[bcl] * f3i);
            zrow[512 + 338 + f] = f2bf(Yr[bcl] * f3i + Yi[bcl] * f3r);
        }
    }
    // zero pads
    if (tid < BCB_ * 10) {
        int bcl = tid / 10, o = tid - bcl * 10;
        int bc = bc0 + bcl;
        if (bc < BCN_) {
            unsigned short* zrow = zbf + (size_t)bc * 1024;
            if (o < 5) zrow[507 + o] = 0;
            else       zrow[1019 + (o - 5)] = 0;
        }
    }
}

// ================= K6: mixing + irfft fused (mixed stays in LDS) =============
__global__ __launch_bounds__(256) void k_mixir(const unsigned short* __restrict__ zbf,
                                               const unsigned short* __restrict__ W2sw,
                                               const float* __restrict__ bm_re,
                                               const float* __restrict__ bm_im,
                                               const unsigned short* __restrict__ Tir,
                                               const float* __restrict__ full,
                                               const float* __restrict__ muv,
                                               const float* __restrict__ nrm,
                                               float* __restrict__ ytmp) {
    __shared__ unsigned short Am[32 * 360];
    int bc0 = blockIdx.x * 32;
    int tid = threadIdx.x, w = tid >> 6, lane = tid & 63;
    int r15 = lane & 15, kg = lane >> 4;

    // ---- phase 1: mixing GEMM (K=1024, N=352) ----
    {
        const int NTB[5] = {0, 6, 12, 17, 22};
        int nt0 = NTB[w], ntn = NTB[w + 1] - nt0;
        f32x4 acc[2][6];
        #pragma unroll
        for (int mf = 0; mf < 2; ++mf)
            #pragma unroll
            for (int j = 0; j < 6; ++j) acc[mf][j] = (f32x4){0.f, 0.f, 0.f, 0.f};
        for (int kc = 0; kc < 32; ++kc) {
            short8v a[2];
            #pragma unroll
            for (int mf = 0; mf < 2; ++mf)
                a[mf] = *(const short8v*)(zbf + ((size_t)(bc0 + mf * 16 + r15) * 1024 + kc * 32 + kg * 8));
            #pragma unroll
            for (int j = 0; j < 6; ++j) {
                if (j >= ntn) continue;
                short8v bfr = *(const short8v*)(W2sw + ((size_t)(kc * 22 + nt0 + j) * 512 + lane * 8));
                #pragma unroll
                for (int mf = 0; mf < 2; ++mf)
                    acc[mf][j] = __builtin_amdgcn_mfma_f32_16x16x32_bf16(a[mf], bfr, acc[mf][j], 0, 0, 0);
            }
        }
        #pragma unroll
        for (int mf = 0; mf < 2; ++mf)
            #pragma unroll
            for (int j = 0; j < 6; ++j) {
                if (j >= ntn) continue;
                int col = (nt0 + j) * 16 + r15;
                #pragma unroll
                for (int reg = 0; reg < 4; ++reg) {
                    int row = mf * 16 + kg * 4 + reg;
                    float v = 0.f;
                    if (col < 2 * FREQ_) {
                        int g = col >> 1;
                        float bias = (col & 1) ? bm_im[g] : bm_re[g];
                        float wgt = (g == 0 || g == FREQ_ - 1) ? 1.0f : 2.0f;
                        v = (acc[mf][j][reg] + bias) * (wgt / (float)H_);
                    }
                    Am[row * 360 + col] = f2bf(v);
                }
            }
    }
    __syncthreads();

    // ---- phase 2: irfft GEMM (K=352, N=336), A from LDS ----
    {
        const int NTB[5] = {0, 6, 11, 16, 21};
        int nt0 = NTB[w], ntn = NTB[w + 1] - nt0;
        f32x4 acc[2][6];
        #pragma unroll
        for (int mf = 0; mf < 2; ++mf)
            #pragma unroll
            for (int j = 0; j < 6; ++j) acc[mf][j] = (f32x4){0.f, 0.f, 0.f, 0.f};
        for (int kc = 0; kc < 11; ++kc) {
            short8v a[2];
            #pragma unroll
            for (int mf = 0; mf < 2; ++mf)
                a[mf] = *(const short8v*)(Am + (size_t)(mf * 16 + r15) * 360 + kc * 32 + kg * 8);
            #pragma unroll
            for (int j = 0; j < 6; ++j) {
                if (j >= ntn) continue;
                short8v bfr = *(const short8v*)(Tir + ((size_t)(kc * 21 + nt0 + j) * 512 + lane * 8));
                #pragma unroll
                for (int mf = 0; mf < 2; ++mf)
                    acc[mf][j] = __builtin_amdgcn_mfma_f32_16x16x32_bf16(a[mf], bfr, acc[mf][j], 0, 0, 0);
            }
        }
        #pragma unroll
        for (int mf = 0; mf < 2; ++mf)
            #pragma unroll
            for (int j = 0; j < 6; ++j) {
                if (j >= ntn) continue;
                int h = (nt0 + j) * 16 + r15;
                #pragma unroll
                for (int reg = 0; reg < 4; ++reg) {
                    int bc = bc0 + mf * 16 + kg * 4 + reg;
                    float y = (full[(size_t)bc * LH_ + L_ + h] + acc[mf][j][reg]) * nrm[bc] + muv[bc];
                    ytmp[(size_t)bc * H_ + h] = y;
                }
            }
    }
}

// ================= K8: transpose ytmp[b][c][h] -> out[b][h][c] ===============
__global__ __launch_bounds__(256) void k_out_t(const float* __restrict__ ytmp,
                                               float* __restrict__ out) {
    __shared__ float tile[32][33];
    int b = blockIdx.z;
    int h0 = blockIdx.x * 32, c0 = blockIdx.y * 32;
    int tx = threadIdx.x & 31, ty = threadIdx.x >> 5;
    #pragma unroll
    for (int i = 0; i < 4; ++i) {
        int cc = c0 + ty + i * 8, hh = h0 + tx;
        if (cc < C_ && hh < H_)
            tile[ty + i * 8][tx] = ytmp[((size_t)b * C_ + cc) * H_ + hh];
    }
    __syncthreads();
    #pragma unroll
    for (int i = 0; i < 4; ++i) {
        int hh = h0 + ty + i * 8, cc = c0 + tx;
        if (cc < C_ && hh < H_)
            out[((size_t)b * H_ + hh) * C_ + cc] = tile[tx][ty + i * 8];
    }
}

extern "C" void kernel_launch(void* const* d_in, const int* in_sizes, int n_in,
                              void* d_out, int out_size, void* d_ws, size_t ws_size,
                              hipStream_t stream) {
    const float* x     = (const float*)d_in[0];
    const float* r     = (const float*)d_in[1];
    const float* Wb    = (const float*)d_in[2];
    const float* bb    = (const float*)d_in[3];
    const float* Wc    = (const float*)d_in[4];
    const float* bcv   = (const float*)d_in[5];
    const float* st_re = (const float*)d_in[6];
    const float* st_im = (const float*)d_in[7];
    const float* Wm_re = (const float*)d_in[8];
    const float* Wm_im = (const float*)d_in[9];
    const float* bm_re = (const float*)d_in[10];
    const float* bm_im = (const float*)d_in[11];
    const int* leader  = (const int*)d_in[12];
    const int* shiftp  = (const int*)d_in[13];
    float* out = (float*)d_out;

    char* w = (char*)d_ws;
    auto carve = [&](size_t bytes) {
        char* p = w;
        w += (bytes + 255) & ~(size_t)255;
        return (void*)p;
    };
    unsigned short* Tdft = (unsigned short*)carve((size_t)11 * 22 * 512 * 2);
    unsigned short* Tir  = (unsigned short*)carve((size_t)11 * 21 * 512 * 2);
    unsigned short* W2   = (unsigned short*)carve((size_t)32 * 22 * 512 * 2);
    unsigned short* Wbsw = (unsigned short*)carve((size_t)16 * 21 * 512 * 2);
    float4*         stf4 = (float4*)carve((size_t)64 * FREQ_ * 16);
    float2*         stg3 = (float2*)carve((size_t)8 * FREQ_ * 8);
    float*          full = (float*)carve((size_t)BCN_ * LH_ * 4);
    unsigned short* xnbf = (unsigned short*)carve((size_t)BCN_ * L_ * 2);
    float*          muv  = (float*)carve((size_t)BCN_ * 4);
    float*          nrm  = (float*)carve((size_t)BCN_ * 4);
    float*          pbuf = (float*)carve((size_t)BCN_ * 8 * 4);
    unsigned short* zbf  = (unsigned short*)carve((size_t)BCN_ * 1024 * 2);
    float*          ytmp = (float*)carve((size_t)BCN_ * H_ * 4);

    hipLaunchKernelGGL(k_prep_dft, dim3(11 * 22), dim3(64), 0, stream, Tdft);
    hipLaunchKernelGGL(k_prep_ir,  dim3(11 * 21), dim3(64), 0, stream, Tir);
    hipLaunchKernelGGL(k_prep_w2,  dim3(32 * 22), dim3(64), 0, stream, Wm_re, Wm_im, W2);
    hipLaunchKernelGGL(k_prep_wb,  dim3(16 * 21), dim3(64), 0, stream, Wb, Wbsw);
    hipLaunchKernelGGL(k_prep_st2, dim3((64 * FREQ_ + 255) / 256), dim3(256), 0, stream,
                       st_re, st_im, stf4, stg3);
    hipLaunchKernelGGL(k_ln2, dim3(6, 32), dim3(256), 0, stream, x, full, xnbf, muv, nrm);
    hipLaunchKernelGGL(k_yhat, dim3(BCN_ / 32), dim3(256), 0, stream, xnbf, Wbsw, bb, full);
    hipLaunchKernelGGL(k_p2, dim3(BCN_ / 16), dim3(256), 0, stream, full, r, Wc, bcv, pbuf);
    hipLaunchKernelGGL(k_dftz, dim3((BCN_ + BCB_ - 1) / BCB_), dim3(256), 0, stream,
                       full, leader, shiftp, Tdft, pbuf, stf4, stg3, zbf);
    hipLaunchKernelGGL(k_mixir, dim3(BCN_ / 32), dim3(256), 0, stream,
                       zbf, W2, bm_re, bm_im, Tir, full, muv, nrm, ytmp);
    hipLaunchKernelGGL(k_out_t, dim3((H_ + 31) / 32, (C_ + 31) / 32, B_), dim3(256), 0, stream,
                       ytmp, out);
}

// Round 6
// 397.735 us; speedup vs baseline: 1.2527x; 1.2527x over previous
//
#include <hip/hip_runtime.h>
#include <math.h>

#define B_ 32
#define L_ 512
#define H_ 336
#define C_ 321
#define K_ 8
#define S_ 8
#define FREQ_ 169   // H/2+1
#define G_ 17       // 2K+1
#define LH_ 848     // L+H
#define F_FEAT 520  // L+K
#define EPS_ 1e-5f
#define BCN_ (B_ * C_)    // 10272
#define NROW_ (BCN_ * 9)  // 92448 signal rows
#define NROWP_ 92480      // padded to 64
#define ZNBC_ 8           // bc per k_z3 block

#ifndef M_PIf
#define M_PIf 3.14159265358979323846f
#endif

typedef __attribute__((ext_vector_type(8))) short short8v;
typedef __attribute__((ext_vector_type(4))) float f32x4;

__device__ __forceinline__ unsigned short f2bf(float x) {
    unsigned u = __builtin_bit_cast(unsigned, x);
    u += 0x7FFFu + ((u >> 16) & 1u);
    return (unsigned short)(u >> 16);
}
__device__ __forceinline__ float bf2f(unsigned short h) {
    return __builtin_bit_cast(float, (unsigned)h << 16);
}

// ================= prep kernels: build MFMA-fragment-swizzled B matrices ==========
// Fragment layout (16x16x32 bf16): b-frag lane l holds B[kc*32 + (l>>4)*8 + i][nt*16 + (l&15)].

// DFT table: K=352 (336 used), N=352 (338 used). col 2f=cos(2pi k f/H), 2f+1=-sin.
__global__ void k_prep_dft(unsigned short* __restrict__ T) {   // grid 11*22, 64 thr
    int blk = blockIdx.x, kc = blk / 22, nt = blk % 22, lane = threadIdx.x;
    int n = nt * 16 + (lane & 15);
    int kb = kc * 32 + (lane >> 4) * 8;
    int f = n >> 1;
    unsigned short* dst = T + (size_t)blk * 512 + lane * 8;
    for (int i = 0; i < 8; ++i) {
        int k = kb + i;
        float val = 0.f;
        if (k < H_ && n < 2 * FREQ_) {
            int m = (k * f) % H_;
            float s, c;
            sincosf((float)m * (2.0f * M_PIf / (float)H_), &s, &c);
            val = (n & 1) ? -s : c;
        }
        dst[i] = f2bf(val);
    }
}

// irfft table: K=352 (338 used; row 2f = cos, 2f+1 = -sin), N=336.
__global__ void k_prep_ir(unsigned short* __restrict__ T) {    // grid 11*21, 64 thr
    int blk = blockIdx.x, kc = blk / 21, nt = blk % 21, lane = threadIdx.x;
    int h = nt * 16 + (lane & 15);
    int kb = kc * 32 + (lane >> 4) * 8;
    unsigned short* dst = T + (size_t)blk * 512 + lane * 8;
    for (int i = 0; i < 8; ++i) {
        int k = kb + i;
        float val = 0.f;
        if (k < 2 * FREQ_) {
            int f = k >> 1;
            int m = (f * h) % H_;
            float s, c;
            sincosf((float)m * (2.0f * M_PIf / (float)H_), &s, &c);
            val = (k & 1) ? -s : c;
        }
        dst[i] = f2bf(val);
    }
}

// Mixing matrix: K=1024 (rows 0..506 = zr, 512..1018 = zi), N=352 (338 used).
__global__ void k_prep_w2(const float* __restrict__ Wm_re, const float* __restrict__ Wm_im,
                          unsigned short* __restrict__ T) {    // grid 32*22, 64 thr
    int blk = blockIdx.x, kc = blk / 22, nt = blk % 22, lane = threadIdx.x;
    int n = nt * 16 + (lane & 15);
    int kb = kc * 32 + (lane >> 4) * 8;
    int g = n >> 1;
    unsigned short* dst = T + (size_t)blk * 512 + lane * 8;
    for (int i = 0; i < 8; ++i) {
        int k = kb + i;
        float val = 0.f;
        if (n < 2 * FREQ_) {
            if (k < 3 * FREQ_) {
                int j = k;
                val = (n & 1) ? Wm_im[(size_t)g * (3 * FREQ_) + j]
                              : Wm_re[(size_t)g * (3 * FREQ_) + j];
            } else if (k >= 512 && k < 512 + 3 * FREQ_) {
                int j = k - 512;
                val = (n & 1) ? Wm_re[(size_t)g * (3 * FREQ_) + j]
                              : -Wm_im[(size_t)g * (3 * FREQ_) + j];
            }
        }
        dst[i] = f2bf(val);
    }
}

// Wb for y_hat GEMM: B[k][n] = Wb[n][k]. K=512, N=336.
__global__ void k_prep_wb(const float* __restrict__ Wb, unsigned short* __restrict__ T) { // grid 16*21, 64 thr
    int blk = blockIdx.x, kc = blk / 21, nt = blk % 21, lane = threadIdx.x;
    int n = nt * 16 + (lane & 15);
    int kb = kc * 32 + (lane >> 4) * 8;
    unsigned short* dst = T + (size_t)blk * 512 + lane * 8;
    for (int i = 0; i < 8; ++i) {
        int k = kb + i;
        dst[i] = f2bf(Wb[(size_t)n * L_ + k]);
    }
}

// states repack, f-major:
// stf4[(k*8+s)*169 + f] = {st[s][k][f].re, .im, st[s][8+k][f].re, .im}
// stg3[s*169 + f]       = {st[s][16][f].re, .im}
__global__ __launch_bounds__(256) void k_prep_st2(const float* __restrict__ st_re,
                                                  const float* __restrict__ st_im,
                                                  float4* __restrict__ stf4,
                                                  float2* __restrict__ stg3) {
    int idx = blockIdx.x * 256 + threadIdx.x;
    if (idx < 64 * FREQ_) {
        int row = idx / FREQ_, f = idx % FREQ_;
        int k = row >> 3, s = row & 7;
        size_t b1 = (size_t)s * (G_ * FREQ_) + (size_t)k * FREQ_ + f;
        size_t b2 = (size_t)s * (G_ * FREQ_) + (size_t)(8 + k) * FREQ_ + f;
        stf4[idx] = make_float4(st_re[b1], st_im[b1], st_re[b2], st_im[b2]);
    }
    if (idx < 8 * FREQ_) {
        int s = idx / FREQ_, f = idx % FREQ_;
        size_t b3 = (size_t)s * (G_ * FREQ_) + (size_t)16 * FREQ_ + f;
        stg3[idx] = make_float2(st_re[b3], st_im[b3]);
    }
}

// ================= K1: LayerNorm, coalesced + LDS transpose =================
__global__ __launch_bounds__(256) void k_ln2(const float* __restrict__ x,
                                             float* __restrict__ full,
                                             unsigned short* __restrict__ xnbf,
                                             float* __restrict__ muv,
                                             float* __restrict__ nrm) {
    __shared__ float tl[64][65];
    __shared__ float red_s[4][64], red_q[4][64];
    __shared__ float sMu[64], sInv[64];
    int tid = threadIdx.x, w = tid >> 6, lane = tid & 63;
    int b = blockIdx.y, c0 = blockIdx.x * 64;
    int c = c0 + lane;
    bool valid = (c < C_);
    const float* xb = x + ((size_t)b * L_) * C_;

    float s = 0.f, q = 0.f;
    for (int l = w; l < L_; l += 4) {
        float v = valid ? xb[(size_t)l * C_ + c] : 0.f;
        s += v; q += v * v;
    }
    red_s[w][lane] = s; red_q[w][lane] = q;
    __syncthreads();
    if (w == 0) {
        float S = red_s[0][lane] + red_s[1][lane] + red_s[2][lane] + red_s[3][lane];
        float Q = red_q[0][lane] + red_q[1][lane] + red_q[2][lane] + red_q[3][lane];
        float mu = S / (float)L_;
        float var = Q / (float)L_ - mu * mu;
        float n = sqrtf(var + EPS_);
        sMu[lane] = mu; sInv[lane] = 1.0f / n;
        if (valid) { muv[(size_t)b * C_ + c] = mu; nrm[(size_t)b * C_ + c] = n; }
    }
    __syncthreads();
    float mu = sMu[lane], inv = sInv[lane];

    for (int l0 = 0; l0 < L_; l0 += 64) {
        for (int li = w; li < 64; li += 4) {
            float v = valid ? xb[(size_t)(l0 + li) * C_ + c] : 0.f;
            tl[li][lane] = (v - mu) * inv;
        }
        __syncthreads();
        for (int cr = w; cr < 64; cr += 4) {
            int cc = c0 + cr;
            if (cc < C_) {
                size_t bc = (size_t)b * C_ + cc;
                full[bc * LH_ + l0 + lane] = tl[lane][cr];
                if (lane < 32) {
                    unsigned pk = (unsigned)f2bf(tl[2 * lane][cr]) |
                                  ((unsigned)f2bf(tl[2 * lane + 1][cr]) << 16);
                    ((unsigned*)xnbf)[bc * 256 + l0 / 2 + lane] = pk;
                }
            }
        }
        __syncthreads();
    }
}

// ================= K2: y_hat via MFMA =======================================
__global__ __launch_bounds__(256) void k_yhat(const unsigned short* __restrict__ xnbf,
                                              const unsigned short* __restrict__ Wbsw,
                                              const float* __restrict__ bb,
                                              float* __restrict__ full) {
    int bc0 = blockIdx.x * 32;
    int tid = threadIdx.x, w = tid >> 6, lane = tid & 63;
    const int NTB[5] = {0, 6, 11, 16, 21};
    int nt0 = NTB[w], ntn = NTB[w + 1] - nt0;
    int r15 = lane & 15, kg = lane >> 4;
    f32x4 acc[2][6];
    #pragma unroll
    for (int mf = 0; mf < 2; ++mf)
        #pragma unroll
        for (int j = 0; j < 6; ++j) acc[mf][j] = (f32x4){0.f, 0.f, 0.f, 0.f};
    for (int kc = 0; kc < 16; ++kc) {
        short8v a[2];
        #pragma unroll
        for (int mf = 0; mf < 2; ++mf)
            a[mf] = *(const short8v*)(xnbf + ((size_t)(bc0 + mf * 16 + r15) * L_ + kc * 32 + kg * 8));
        #pragma unroll
        for (int j = 0; j < 6; ++j) {
            if (j >= ntn) continue;
            short8v bfr = *(const short8v*)(Wbsw + ((size_t)(kc * 21 + nt0 + j) * 512 + lane * 8));
            #pragma unroll
            for (int mf = 0; mf < 2; ++mf)
                acc[mf][j] = __builtin_amdgcn_mfma_f32_16x16x32_bf16(a[mf], bfr, acc[mf][j], 0, 0, 0);
        }
    }
    #pragma unroll
    for (int mf = 0; mf < 2; ++mf)
        #pragma unroll
        for (int j = 0; j < 6; ++j) {
            if (j >= ntn) continue;
            int n_ = (nt0 + j) * 16 + r15;
            #pragma unroll
            for (int reg = 0; reg < 4; ++reg) {
                int bc = bc0 + mf * 16 + kg * 4 + reg;
                full[(size_t)bc * LH_ + L_ + n_] = acc[mf][j][reg] + bb[n_];
            }
        }
}

// ================= K3: r_soft + feat @ Wc^T + softmax -> p (Wc in LDS) =======
__global__ __launch_bounds__(256) void k_p2(const float* __restrict__ full,
                                            const float* __restrict__ r,
                                            const float* __restrict__ Wc,
                                            const float* __restrict__ bcv,
                                            float* __restrict__ p_out) {
    __shared__ float WcS[8 * F_FEAT];
    __shared__ float rsS[16][8];
    __shared__ float bcS[8];
    int tid = threadIdx.x, w = tid >> 6, lane = tid & 63;
    int bc0 = blockIdx.x * 16;
    for (int i = tid; i < 8 * F_FEAT; i += 256) WcS[i] = Wc[i];
    if (tid < 8) bcS[tid] = bcv[tid];
    if (tid < 16) {
        int bc = bc0 + tid;
        const float* rr = r + (size_t)bc * K_;
        float a[8]; float m = 1.0f;
        #pragma unroll
        for (int k = 0; k < 8; ++k) { a[k] = fabsf(rr[k]); m = fmaxf(m, a[k]); }
        float Z = expf(1.0f - m);
        float e[8];
        #pragma unroll
        for (int k = 0; k < 8; ++k) { e[k] = expf(a[k] - m); Z += e[k]; }
        float inv = 1.0f / Z;
        #pragma unroll
        for (int k = 0; k < 8; ++k) rsS[tid][k] = e[k] * inv;
    }
    __syncthreads();

    for (int i = 0; i < 4; ++i) {
        int bcl = w * 4 + i;
        int bc = bc0 + bcl;
        const float* xrow = full + (size_t)bc * LH_;
        float acc[8] = {0.f, 0.f, 0.f, 0.f, 0.f, 0.f, 0.f, 0.f};
        #pragma unroll
        for (int t = 0; t < 8; ++t) {
            int f = lane + t * 64;
            float xf = xrow[f];
            #pragma unroll
            for (int s = 0; s < 8; ++s) acc[s] += xf * WcS[s * F_FEAT + f];
        }
        if (lane < 8) {
            float xf = rsS[bcl][lane];
            #pragma unroll
            for (int s = 0; s < 8; ++s) acc[s] += xf * WcS[s * F_FEAT + L_ + lane];
        }
        #pragma unroll
        for (int s = 0; s < 8; ++s) {
            #pragma unroll
            for (int off = 32; off > 0; off >>= 1) acc[s] += __shfl_down(acc[s], off);
        }
        if (lane == 0) {
            float m = -1e30f;
            #pragma unroll
            for (int s = 0; s < 8; ++s) { acc[s] += bcS[s]; m = fmaxf(m, acc[s]); }
            float Z = 0.f; float e[8];
            #pragma unroll
            for (int s = 0; s < 8; ++s) { e[s] = expf(acc[s] - m); Z += e[s]; }
            float inv = 1.0f / Z;
            #pragma unroll
            for (int s = 0; s < 8; ++s) p_out[(size_t)bc * 8 + s] = e[s] * inv;
        }
    }
}

// ================= K4a: gather signal rows -> sigbf[row][352] bf16 ===========
// row = bc*9 + k; k<8: window of leader channel; k=8: y_hat. Cols 336..351 = 0.
// grid = NROW_/16, 256 thr (4 waves x 4 rows).
__global__ __launch_bounds__(256) void k_gather(const float* __restrict__ full,
                                                const int* __restrict__ leader,
                                                const int* __restrict__ shiftp,
                                                unsigned* __restrict__ sig32) {
    int tid = threadIdx.x, w = tid >> 6, lane = tid & 63;
    int r0 = blockIdx.x * 16 + w * 4;
    for (int i = 0; i < 4; ++i) {
        int r = r0 + i;
        int bc = r / 9, k = r - bc * 9;
        int b = bc / C_;
        const float* src;
        if (k < 8) {
            int lead = leader[(size_t)bc * K_ + k];
            int sh = shiftp[(size_t)bc * K_ + k];
            src = full + ((size_t)b * C_ + lead) * LH_ + (L_ - sh);
        } else {
            src = full + (size_t)bc * LH_ + L_;
        }
        unsigned* dst = sig32 + (size_t)r * 176;
        #pragma unroll
        for (int t = 0; t < 3; ++t) {
            int j = lane + t * 64;
            if (j < 176) {
                unsigned pk = 0;
                if (j < 168) {
                    float2 v = *(const float2*)(src + 2 * j);
                    pk = (unsigned)f2bf(v.x) | ((unsigned)f2bf(v.y) << 16);
                }
                dst[j] = pk;
            }
        }
    }
}

// ================= K4b: DFT as pure streaming MFMA GEMM =====================
// M = NROWP_ (64/block), K = 352, N = 352. No LDS.
// X[row][352] bf16: col 2f = Re, 2f+1 = Im.
__global__ __launch_bounds__(256) void k_dft2(const unsigned short* __restrict__ sigbf,
                                              const unsigned short* __restrict__ Tsw,
                                              unsigned short* __restrict__ Xbf) {
    int row0 = blockIdx.x * 64;
    int tid = threadIdx.x, w = tid >> 6, lane = tid & 63;
    const int NTB[5] = {0, 6, 12, 17, 22};
    int nt0 = NTB[w], ntn = NTB[w + 1] - nt0;
    int r15 = lane & 15, kg = lane >> 4;
    f32x4 acc[4][6];
    #pragma unroll
    for (int mf = 0; mf < 4; ++mf)
        #pragma unroll
        for (int j = 0; j < 6; ++j) acc[mf][j] = (f32x4){0.f, 0.f, 0.f, 0.f};
    for (int kc = 0; kc < 11; ++kc) {
        short8v a[4];
        #pragma unroll
        for (int mf = 0; mf < 4; ++mf)
            a[mf] = *(const short8v*)(sigbf + ((size_t)(row0 + mf * 16 + r15) * 352 + kc * 32 + kg * 8));
        #pragma unroll
        for (int j = 0; j < 6; ++j) {
            if (j >= ntn) continue;
            short8v bfr = *(const short8v*)(Tsw + ((size_t)(kc * 22 + nt0 + j) * 512 + lane * 8));
            #pragma unroll
            for (int mf = 0; mf < 4; ++mf)
                acc[mf][j] = __builtin_amdgcn_mfma_f32_16x16x32_bf16(a[mf], bfr, acc[mf][j], 0, 0, 0);
        }
    }
    #pragma unroll
    for (int mf = 0; mf < 4; ++mf)
        #pragma unroll
        for (int j = 0; j < 6; ++j) {
            if (j >= ntn) continue;
            int col = (nt0 + j) * 16 + r15;
            #pragma unroll
            for (int reg = 0; reg < 4; ++reg) {
                int row = row0 + mf * 16 + kg * 4 + reg;
                Xbf[(size_t)row * 352 + col] = f2bf(acc[mf][j][reg]);
            }
        }
}

// ================= K5: filter-combine X -> z (f-major, 8-bc register reuse) ==
__global__ __launch_bounds__(256) void k_z3(const unsigned* __restrict__ X32,
                                            const float* __restrict__ pbuf,
                                            const float4* __restrict__ stf4,
                                            const float2* __restrict__ stg3,
                                            unsigned short* __restrict__ zbf) {
    __shared__ float psL[ZNBC_][8];
    int tid = threadIdx.x;
    int bc0 = blockIdx.x * ZNBC_;
    if (tid < ZNBC_ * 8) {
        int bcl = tid >> 3, s = tid & 7;
        psL[bcl][s] = pbuf[(size_t)(bc0 + bcl) * 8 + s];
    }
    __syncthreads();

    if (tid < FREQ_) {
        int f = tid;
        float z1r[ZNBC_], z1i[ZNBC_], z2r[ZNBC_], z2i[ZNBC_], Yr[ZNBC_], Yi[ZNBC_];
        #pragma unroll
        for (int bcl = 0; bcl < ZNBC_; ++bcl) {
            z1r[bcl] = z1i[bcl] = z2r[bcl] = z2i[bcl] = 0.f;
            unsigned v = X32[((size_t)(bc0 + bcl) * 9 + 8) * 176 + f];
            Yr[bcl] = bf2f((unsigned short)(v & 0xffff));
            Yi[bcl] = bf2f((unsigned short)(v >> 16));
        }
        for (int k = 0; k < 8; ++k) {
            float4 stv[8];
            #pragma unroll
            for (int s = 0; s < 8; ++s) stv[s] = stf4[(size_t)(k * 8 + s) * FREQ_ + f];
            #pragma unroll
            for (int bcl = 0; bcl < ZNBC_; ++bcl) {
                float f1r = 0.f, f1i = 0.f, f2r = 0.f, f2i = 0.f;
                #pragma unroll
                for (int s = 0; s < 8; ++s) {
                    float p = psL[bcl][s];
                    f1r += p * stv[s].x; f1i += p * stv[s].y;
                    f2r += p * stv[s].z; f2i += p * stv[s].w;
                }
                unsigned v = X32[((size_t)(bc0 + bcl) * 9 + k) * 176 + f];
                float Xr = bf2f((unsigned short)(v & 0xffff));
                float Xi = bf2f((unsigned short)(v >> 16));
                float ar = Xr * f1r - Xi * f1i;
                float ai = Xr * f1i + Xi * f1r;
                z1r[bcl] += ar; z1i[bcl] += ai;
                float dr = ar - Yr[bcl], di = ai - Yi[bcl];
                z2r[bcl] += dr * f2r - di * f2i;
                z2i[bcl] += dr * f2i + di * f2r;
            }
        }
        #pragma unroll
        for (int bcl = 0; bcl < ZNBC_; ++bcl) {
            int bc = bc0 + bcl;
            float f3r = 0.f, f3i = 0.f;
            #pragma unroll
            for (int s = 0; s < 8; ++s) {
                float2 v3 = stg3[(size_t)s * FREQ_ + f];
                float p = psL[bcl][s];
                f3r += p * v3.x; f3i += p * v3.y;
            }
            unsigned short* zrow = zbf + (size_t)bc * 1024;
            zrow[f]       = f2bf(z1r[bcl]);  zrow[512 + f]       = f2bf(z1i[bcl]);
            zrow[169 + f] = f2bf(z2r[bcl]);  zrow[512 + 169 + f] = f2bf(z2i[bcl]);
            zrow[338 + f] = f2bf(Yr[bcl] * f3r - Yi[bcl] * f3i);
            zrow[512 + 338 + f] = f2bf(Yr[bcl] * f3i + Yi[bcl] * f3r);
        }
    } else if (tid >= 176 && tid < 176 + ZNBC_ * 10) {
        int t = tid - 176;
        int bcl = t / 10, o = t - bcl * 10;
        unsigned short* zrow = zbf + (size_t)(bc0 + bcl) * 1024;
        if (o < 5) zrow[507 + o] = 0;
        else       zrow[1019 + (o - 5)] = 0;
    }
}

// ================= K6: mixing + irfft fused (mixed stays in LDS) =============
__global__ __launch_bounds__(256) void k_mixir(const unsigned short* __restrict__ zbf,
                                               const unsigned short* __restrict__ W2sw,
                                               const float* __restrict__ bm_re,
                                               const float* __restrict__ bm_im,
                                               const unsigned short* __restrict__ Tir,
                                               const float* __restrict__ full,
                                               const float* __restrict__ muv,
                                               const float* __restrict__ nrm,
                                               float* __restrict__ ytmp) {
    __shared__ unsigned short Am[32 * 360];
    int bc0 = blockIdx.x * 32;
    int tid = threadIdx.x, w = tid >> 6, lane = tid & 63;
    int r15 = lane & 15, kg = lane >> 4;

    {
        const int NTB[5] = {0, 6, 12, 17, 22};
        int nt0 = NTB[w], ntn = NTB[w + 1] - nt0;
        f32x4 acc[2][6];
        #pragma unroll
        for (int mf = 0; mf < 2; ++mf)
            #pragma unroll
            for (int j = 0; j < 6; ++j) acc[mf][j] = (f32x4){0.f, 0.f, 0.f, 0.f};
        for (int kc = 0; kc < 32; ++kc) {
            short8v a[2];
            #pragma unroll
            for (int mf = 0; mf < 2; ++mf)
                a[mf] = *(const short8v*)(zbf + ((size_t)(bc0 + mf * 16 + r15) * 1024 + kc * 32 + kg * 8));
            #pragma unroll
            for (int j = 0; j < 6; ++j) {
                if (j >= ntn) continue;
                short8v bfr = *(const short8v*)(W2sw + ((size_t)(kc * 22 + nt0 + j) * 512 + lane * 8));
                #pragma unroll
                for (int mf = 0; mf < 2; ++mf)
                    acc[mf][j] = __builtin_amdgcn_mfma_f32_16x16x32_bf16(a[mf], bfr, acc[mf][j], 0, 0, 0);
            }
        }
        #pragma unroll
        for (int mf = 0; mf < 2; ++mf)
            #pragma unroll
            for (int j = 0; j < 6; ++j) {
                if (j >= ntn) continue;
                int col = (nt0 + j) * 16 + r15;
                #pragma unroll
                for (int reg = 0; reg < 4; ++reg) {
                    int row = mf * 16 + kg * 4 + reg;
                    float v = 0.f;
                    if (col < 2 * FREQ_) {
                        int g = col >> 1;
                        float bias = (col & 1) ? bm_im[g] : bm_re[g];
                        float wgt = (g == 0 || g == FREQ_ - 1) ? 1.0f : 2.0f;
                        v = (acc[mf][j][reg] + bias) * (wgt / (float)H_);
                    }
                    Am[row * 360 + col] = f2bf(v);
                }
            }
    }
    __syncthreads();

    {
        const int NTB[5] = {0, 6, 11, 16, 21};
        int nt0 = NTB[w], ntn = NTB[w + 1] - nt0;
        f32x4 acc[2][6];
        #pragma unroll
        for (int mf = 0; mf < 2; ++mf)
            #pragma unroll
            for (int j = 0; j < 6; ++j) acc[mf][j] = (f32x4){0.f, 0.f, 0.f, 0.f};
        for (int kc = 0; kc < 11; ++kc) {
            short8v a[2];
            #pragma unroll
            for (int mf = 0; mf < 2; ++mf)
                a[mf] = *(const short8v*)(Am + (size_t)(mf * 16 + r15) * 360 + kc * 32 + kg * 8);
            #pragma unroll
            for (int j = 0; j < 6; ++j) {
                if (j >= ntn) continue;
                short8v bfr = *(const short8v*)(Tir + ((size_t)(kc * 21 + nt0 + j) * 512 + lane * 8));
                #pragma unroll
                for (int mf = 0; mf < 2; ++mf)
                    acc[mf][j] = __builtin_amdgcn_mfma_f32_16x16x32_bf16(a[mf], bfr, acc[mf][j], 0, 0, 0);
            }
        }
        #pragma unroll
        for (int mf = 0; mf < 2; ++mf)
            #pragma unroll
            for (int j = 0; j < 6; ++j) {
                if (j >= ntn) continue;
                int h = (nt0 + j) * 16 + r15;
                #pragma unroll
                for (int reg = 0; reg < 4; ++reg) {
                    int bc = bc0 + mf * 16 + kg * 4 + reg;
                    float y = (full[(size_t)bc * LH_ + L_ + h] + acc[mf][j][reg]) * nrm[bc] + muv[bc];
                    ytmp[(size_t)bc * H_ + h] = y;
                }
            }
    }
}

// ================= K8: transpose ytmp[b][c][h] -> out[b][h][c] ===============
__global__ __launch_bounds__(256) void k_out_t(const float* __restrict__ ytmp,
                                               float* __restrict__ out) {
    __shared__ float tile[32][33];
    int b = blockIdx.z;
    int h0 = blockIdx.x * 32, c0 = blockIdx.y * 32;
    int tx = threadIdx.x & 31, ty = threadIdx.x >> 5;
    #pragma unroll
    for (int i = 0; i < 4; ++i) {
        int cc = c0 + ty + i * 8, hh = h0 + tx;
        if (cc < C_ && hh < H_)
            tile[ty + i * 8][tx] = ytmp[((size_t)b * C_ + cc) * H_ + hh];
    }
    __syncthreads();
    #pragma unroll
    for (int i = 0; i < 4; ++i) {
        int hh = h0 + ty + i * 8, cc = c0 + tx;
        if (cc < C_ && hh < H_)
            out[((size_t)b * H_ + hh) * C_ + cc] = tile[tx][ty + i * 8];
    }
}

extern "C" void kernel_launch(void* const* d_in, const int* in_sizes, int n_in,
                              void* d_out, int out_size, void* d_ws, size_t ws_size,
                              hipStream_t stream) {
    const float* x     = (const float*)d_in[0];
    const float* r     = (const float*)d_in[1];
    const float* Wb    = (const float*)d_in[2];
    const float* bb    = (const float*)d_in[3];
    const float* Wc    = (const float*)d_in[4];
    const float* bcv   = (const float*)d_in[5];
    const float* st_re = (const float*)d_in[6];
    const float* st_im = (const float*)d_in[7];
    const float* Wm_re = (const float*)d_in[8];
    const float* Wm_im = (const float*)d_in[9];
    const float* bm_re = (const float*)d_in[10];
    const float* bm_im = (const float*)d_in[11];
    const int* leader  = (const int*)d_in[12];
    const int* shiftp  = (const int*)d_in[13];
    float* out = (float*)d_out;

    char* w = (char*)d_ws;
    auto carve = [&](size_t bytes) {
        char* p = w;
        w += (bytes + 255) & ~(size_t)255;
        return (void*)p;
    };
    unsigned short* Tdft = (unsigned short*)carve((size_t)11 * 22 * 512 * 2);
    unsigned short* Tir  = (unsigned short*)carve((size_t)11 * 21 * 512 * 2);
    unsigned short* W2   = (unsigned short*)carve((size_t)32 * 22 * 512 * 2);
    unsigned short* Wbsw = (unsigned short*)carve((size_t)16 * 21 * 512 * 2);
    float4*         stf4 = (float4*)carve((size_t)64 * FREQ_ * 16);
    float2*         stg3 = (float2*)carve((size_t)8 * FREQ_ * 8);
    float*          full = (float*)carve((size_t)BCN_ * LH_ * 4);
    unsigned short* xnbf = (unsigned short*)carve((size_t)BCN_ * L_ * 2);
    float*          muv  = (float*)carve((size_t)BCN_ * 4);
    float*          nrm  = (float*)carve((size_t)BCN_ * 4);
    float*          pbuf = (float*)carve((size_t)BCN_ * 8 * 4);
    unsigned short* zbf  = (unsigned short*)carve((size_t)BCN_ * 1024 * 2);
    float*          ytmp = (float*)carve((size_t)BCN_ * H_ * 4);
    unsigned short* sigbf= (unsigned short*)carve((size_t)NROWP_ * 352 * 2);
    unsigned short* Xbf  = (unsigned short*)carve((size_t)NROWP_ * 352 * 2);

    hipLaunchKernelGGL(k_prep_dft, dim3(11 * 22), dim3(64), 0, stream, Tdft);
    hipLaunchKernelGGL(k_prep_ir,  dim3(11 * 21), dim3(64), 0, stream, Tir);
    hipLaunchKernelGGL(k_prep_w2,  dim3(32 * 22), dim3(64), 0, stream, Wm_re, Wm_im, W2);
    hipLaunchKernelGGL(k_prep_wb,  dim3(16 * 21), dim3(64), 0, stream, Wb, Wbsw);
    hipLaunchKernelGGL(k_prep_st2, dim3((64 * FREQ_ + 255) / 256), dim3(256), 0, stream,
                       st_re, st_im, stf4, stg3);
    hipLaunchKernelGGL(k_ln2, dim3(6, 32), dim3(256), 0, stream, x, full, xnbf, muv, nrm);
    hipLaunchKernelGGL(k_yhat, dim3(BCN_ / 32), dim3(256), 0, stream, xnbf, Wbsw, bb, full);
    hipLaunchKernelGGL(k_p2, dim3(BCN_ / 16), dim3(256), 0, stream, full, r, Wc, bcv, pbuf);
    hipLaunchKernelGGL(k_gather, dim3(NROW_ / 16), dim3(256), 0, stream,
                       full, leader, shiftp, (unsigned*)sigbf);
    hipLaunchKernelGGL(k_dft2, dim3(NROWP_ / 64), dim3(256), 0, stream, sigbf, Tdft, Xbf);
    hipLaunchKernelGGL(k_z3, dim3(BCN_ / ZNBC_), dim3(256), 0, stream,
                       (const unsigned*)Xbf, pbuf, stf4, stg3, zbf);
    hipLaunchKernelGGL(k_mixir, dim3(BCN_ / 32), dim3(256), 0, stream,
                       zbf, W2, bm_re, bm_im, Tir, full, muv, nrm, ytmp);
    hipLaunchKernelGGL(k_out_t, dim3((H_ + 31) / 32, (C_ + 31) / 32, B_), dim3(256), 0, stream,
                       ytmp, out);
}

// Round 7
// 333.290 us; speedup vs baseline: 1.4950x; 1.1934x over previous
//
#include <hip/hip_runtime.h>
#include <math.h>

#define B_ 32
#define L_ 512
#define H_ 336
#define C_ 321
#define K_ 8
#define S_ 8
#define FREQ_ 169   // H/2+1
#define G_ 17       // 2K+1
#define LHB_ 848    // L+H (bf16 row length)
#define F_FEAT 520  // L+K
#define EPS_ 1e-5f
#define BCN_ (B_ * C_)    // 10272
#define NROW_ (BCN_ * 9)  // 92448 signal rows
#define NROWP_ 92480      // padded to 64
#define ZNBC_ 8           // bc per k_z3 block

#ifndef M_PIf
#define M_PIf 3.14159265358979323846f
#endif

typedef __attribute__((ext_vector_type(8))) short short8v;
typedef __attribute__((ext_vector_type(4))) float f32x4;

__device__ __forceinline__ unsigned short f2bf(float x) {
    unsigned u = __builtin_bit_cast(unsigned, x);
    u += 0x7FFFu + ((u >> 16) & 1u);
    return (unsigned short)(u >> 16);
}
__device__ __forceinline__ float bf2f(unsigned short h) {
    return __builtin_bit_cast(float, (unsigned)h << 16);
}

// ================= prep kernels: build MFMA-fragment-swizzled B matrices ==========
// Fragment layout (16x16x32 bf16): b-frag lane l holds B[kc*32 + (l>>4)*8 + i][nt*16 + (l&15)].

__global__ void k_prep_dft(unsigned short* __restrict__ T) {   // grid 11*22, 64 thr
    int blk = blockIdx.x, kc = blk / 22, nt = blk % 22, lane = threadIdx.x;
    int n = nt * 16 + (lane & 15);
    int kb = kc * 32 + (lane >> 4) * 8;
    int f = n >> 1;
    unsigned short* dst = T + (size_t)blk * 512 + lane * 8;
    for (int i = 0; i < 8; ++i) {
        int k = kb + i;
        float val = 0.f;
        if (k < H_ && n < 2 * FREQ_) {
            int m = (k * f) % H_;
            float s, c;
            sincosf((float)m * (2.0f * M_PIf / (float)H_), &s, &c);
            val = (n & 1) ? -s : c;
        }
        dst[i] = f2bf(val);
    }
}

__global__ void k_prep_ir(unsigned short* __restrict__ T) {    // grid 11*21, 64 thr
    int blk = blockIdx.x, kc = blk / 21, nt = blk % 21, lane = threadIdx.x;
    int h = nt * 16 + (lane & 15);
    int kb = kc * 32 + (lane >> 4) * 8;
    unsigned short* dst = T + (size_t)blk * 512 + lane * 8;
    for (int i = 0; i < 8; ++i) {
        int k = kb + i;
        float val = 0.f;
        if (k < 2 * FREQ_) {
            int f = k >> 1;
            int m = (f * h) % H_;
            float s, c;
            sincosf((float)m * (2.0f * M_PIf / (float)H_), &s, &c);
            val = (k & 1) ? -s : c;
        }
        dst[i] = f2bf(val);
    }
}

__global__ void k_prep_w2(const float* __restrict__ Wm_re, const float* __restrict__ Wm_im,
                          unsigned short* __restrict__ T) {    // grid 32*22, 64 thr
    int blk = blockIdx.x, kc = blk / 22, nt = blk % 22, lane = threadIdx.x;
    int n = nt * 16 + (lane & 15);
    int kb = kc * 32 + (lane >> 4) * 8;
    int g = n >> 1;
    unsigned short* dst = T + (size_t)blk * 512 + lane * 8;
    for (int i = 0; i < 8; ++i) {
        int k = kb + i;
        float val = 0.f;
        if (n < 2 * FREQ_) {
            if (k < 3 * FREQ_) {
                int j = k;
                val = (n & 1) ? Wm_im[(size_t)g * (3 * FREQ_) + j]
                              : Wm_re[(size_t)g * (3 * FREQ_) + j];
            } else if (k >= 512 && k < 512 + 3 * FREQ_) {
                int j = k - 512;
                val = (n & 1) ? Wm_re[(size_t)g * (3 * FREQ_) + j]
                              : -Wm_im[(size_t)g * (3 * FREQ_) + j];
            }
        }
        dst[i] = f2bf(val);
    }
}

__global__ void k_prep_wb(const float* __restrict__ Wb, unsigned short* __restrict__ T) { // grid 16*21, 64 thr
    int blk = blockIdx.x, kc = blk / 21, nt = blk % 21, lane = threadIdx.x;
    int n = nt * 16 + (lane & 15);
    int kb = kc * 32 + (lane >> 4) * 8;
    unsigned short* dst = T + (size_t)blk * 512 + lane * 8;
    for (int i = 0; i < 8; ++i) {
        int k = kb + i;
        dst[i] = f2bf(Wb[(size_t)n * L_ + k]);
    }
}

// states repack, f-major
__global__ __launch_bounds__(256) void k_prep_st2(const float* __restrict__ st_re,
                                                  const float* __restrict__ st_im,
                                                  float4* __restrict__ stf4,
                                                  float2* __restrict__ stg3) {
    int idx = blockIdx.x * 256 + threadIdx.x;
    if (idx < 64 * FREQ_) {
        int row = idx / FREQ_, f = idx % FREQ_;
        int k = row >> 3, s = row & 7;
        size_t b1 = (size_t)s * (G_ * FREQ_) + (size_t)k * FREQ_ + f;
        size_t b2 = (size_t)s * (G_ * FREQ_) + (size_t)(8 + k) * FREQ_ + f;
        stf4[idx] = make_float4(st_re[b1], st_im[b1], st_re[b2], st_im[b2]);
    }
    if (idx < 8 * FREQ_) {
        int s = idx / FREQ_, f = idx % FREQ_;
        size_t b3 = (size_t)s * (G_ * FREQ_) + (size_t)16 * FREQ_ + f;
        stg3[idx] = make_float2(st_re[b3], st_im[b3]);
    }
}

// ================= K1a: LN partial sums. grid (6, 32, 8) =====================
__global__ __launch_bounds__(256) void k_stats_part(const float* __restrict__ x,
                                                    float2* __restrict__ part) {
    __shared__ float red_s[4][64], red_q[4][64];
    int tid = threadIdx.x, w = tid >> 6, lane = tid & 63;
    int b = blockIdx.y, c0 = blockIdx.x * 64, l0 = blockIdx.z * 64;
    int c = c0 + lane;
    bool valid = (c < C_);
    const float* xb = x + ((size_t)b * L_) * C_;
    float s = 0.f, q = 0.f;
    for (int li = w; li < 64; li += 4) {
        float v = valid ? xb[(size_t)(l0 + li) * C_ + c] : 0.f;
        s += v; q += v * v;
    }
    red_s[w][lane] = s; red_q[w][lane] = q;
    __syncthreads();
    if (w == 0) {
        float S = red_s[0][lane] + red_s[1][lane] + red_s[2][lane] + red_s[3][lane];
        float Q = red_q[0][lane] + red_q[1][lane] + red_q[2][lane] + red_q[3][lane];
        part[(size_t)(((b * 6 + blockIdx.x) * 8) + blockIdx.z) * 64 + lane] = make_float2(S, Q);
    }
}

// ================= K1b: finalize mu / nrm. grid 48, 256 thr ==================
__global__ __launch_bounds__(256) void k_stats_fin(const float2* __restrict__ part,
                                                   float* __restrict__ muv,
                                                   float* __restrict__ nrm) {
    int t = blockIdx.x * 256 + threadIdx.x;      // (b, ctile, cl)
    int b = t / 384, rem = t % 384;
    int ct = rem / 64, cl = rem % 64;
    int c = ct * 64 + cl;
    if (b >= B_ || c >= C_) return;
    float S = 0.f, Q = 0.f;
    #pragma unroll
    for (int ls = 0; ls < 8; ++ls) {
        float2 p = part[(size_t)(((b * 6 + ct) * 8) + ls) * 64 + cl];
        S += p.x; Q += p.y;
    }
    float mu = S / (float)L_;
    float var = Q / (float)L_ - mu * mu;
    float n = sqrtf(var + EPS_);
    muv[(size_t)b * C_ + c] = mu;
    nrm[(size_t)b * C_ + c] = n;
}

// ================= K1c: normalize + transpose -> fullbf (bf16). grid (6,32,8) =
__global__ __launch_bounds__(256) void k_norm(const float* __restrict__ x,
                                              const float* __restrict__ muv,
                                              const float* __restrict__ nrm,
                                              unsigned short* __restrict__ fullbf) {
    __shared__ float tl[64][65];
    int tid = threadIdx.x, w = tid >> 6, lane = tid & 63;
    int b = blockIdx.y, c0 = blockIdx.x * 64, l0 = blockIdx.z * 64;
    int c = c0 + lane;
    bool valid = (c < C_);
    const float* xb = x + ((size_t)b * L_) * C_;
    float mu = valid ? muv[(size_t)b * C_ + c] : 0.f;
    float inv = valid ? (1.0f / nrm[(size_t)b * C_ + c]) : 0.f;
    for (int li = w; li < 64; li += 4) {
        float v = valid ? xb[(size_t)(l0 + li) * C_ + c] : 0.f;
        tl[li][lane] = (v - mu) * inv;
    }
    __syncthreads();
    for (int cr = w; cr < 64; cr += 4) {
        int cc = c0 + cr;
        if (cc < C_ && lane < 32) {
            size_t bc = (size_t)b * C_ + cc;
            unsigned pk = (unsigned)f2bf(tl[2 * lane][cr]) |
                          ((unsigned)f2bf(tl[2 * lane + 1][cr]) << 16);
            ((unsigned*)fullbf)[(bc * LHB_ + l0) / 2 + lane] = pk;
        }
    }
}

// ================= K2: y_hat via MFMA (A from fullbf xn region) ==============
__global__ __launch_bounds__(256) void k_yhat(const unsigned short* __restrict__ fullbf_r,
                                              const unsigned short* __restrict__ Wbsw,
                                              const float* __restrict__ bb,
                                              unsigned short* __restrict__ fullbf_w,
                                              float* __restrict__ yhf) {
    int bc0 = blockIdx.x * 32;
    int tid = threadIdx.x, w = tid >> 6, lane = tid & 63;
    const int NTB[5] = {0, 6, 11, 16, 21};
    int nt0 = NTB[w], ntn = NTB[w + 1] - nt0;
    int r15 = lane & 15, kg = lane >> 4;
    f32x4 acc[2][6];
    #pragma unroll
    for (int mf = 0; mf < 2; ++mf)
        #pragma unroll
        for (int j = 0; j < 6; ++j) acc[mf][j] = (f32x4){0.f, 0.f, 0.f, 0.f};
    for (int kc = 0; kc < 16; ++kc) {
        short8v a[2];
        #pragma unroll
        for (int mf = 0; mf < 2; ++mf)
            a[mf] = *(const short8v*)(fullbf_r + ((size_t)(bc0 + mf * 16 + r15) * LHB_ + kc * 32 + kg * 8));
        #pragma unroll
        for (int j = 0; j < 6; ++j) {
            if (j >= ntn) continue;
            short8v bfr = *(const short8v*)(Wbsw + ((size_t)(kc * 21 + nt0 + j) * 512 + lane * 8));
            #pragma unroll
            for (int mf = 0; mf < 2; ++mf)
                acc[mf][j] = __builtin_amdgcn_mfma_f32_16x16x32_bf16(a[mf], bfr, acc[mf][j], 0, 0, 0);
        }
    }
    #pragma unroll
    for (int mf = 0; mf < 2; ++mf)
        #pragma unroll
        for (int j = 0; j < 6; ++j) {
            if (j >= ntn) continue;
            int n_ = (nt0 + j) * 16 + r15;
            #pragma unroll
            for (int reg = 0; reg < 4; ++reg) {
                int bc = bc0 + mf * 16 + kg * 4 + reg;
                float v = acc[mf][j][reg] + bb[n_];
                fullbf_w[(size_t)bc * LHB_ + L_ + n_] = f2bf(v);
                yhf[(size_t)bc * H_ + n_] = v;
            }
        }
}

// ================= K3: r_soft + feat @ Wc^T + softmax -> p (bf16 xn) =========
__global__ __launch_bounds__(256) void k_p2(const unsigned short* __restrict__ fullbf,
                                            const float* __restrict__ r,
                                            const float* __restrict__ Wc,
                                            const float* __restrict__ bcv,
                                            float* __restrict__ p_out) {
    __shared__ float WcS[8 * F_FEAT];
    __shared__ float rsS[16][8];
    __shared__ float bcS[8];
    int tid = threadIdx.x, w = tid >> 6, lane = tid & 63;
    int bc0 = blockIdx.x * 16;
    for (int i = tid; i < 8 * F_FEAT; i += 256) WcS[i] = Wc[i];
    if (tid < 8) bcS[tid] = bcv[tid];
    if (tid < 16) {
        int bc = bc0 + tid;
        const float* rr = r + (size_t)bc * K_;
        float a[8]; float m = 1.0f;
        #pragma unroll
        for (int k = 0; k < 8; ++k) { a[k] = fabsf(rr[k]); m = fmaxf(m, a[k]); }
        float Z = expf(1.0f - m);
        float e[8];
        #pragma unroll
        for (int k = 0; k < 8; ++k) { e[k] = expf(a[k] - m); Z += e[k]; }
        float inv = 1.0f / Z;
        #pragma unroll
        for (int k = 0; k < 8; ++k) rsS[tid][k] = e[k] * inv;
    }
    __syncthreads();

    for (int i = 0; i < 4; ++i) {
        int bcl = w * 4 + i;
        int bc = bc0 + bcl;
        const unsigned* xrow = (const unsigned*)(fullbf + (size_t)bc * LHB_);
        float acc[8] = {0.f, 0.f, 0.f, 0.f, 0.f, 0.f, 0.f, 0.f};
        #pragma unroll
        for (int t = 0; t < 4; ++t) {
            int j = lane + t * 64;            // u32 pair index, elements 2j, 2j+1
            unsigned v = xrow[j];
            float x0 = bf2f((unsigned short)(v & 0xffff));
            float x1 = bf2f((unsigned short)(v >> 16));
            #pragma unroll
            for (int s = 0; s < 8; ++s)
                acc[s] += x0 * WcS[s * F_FEAT + 2 * j] + x1 * WcS[s * F_FEAT + 2 * j + 1];
        }
        if (lane < 8) {
            float xf = rsS[bcl][lane];
            #pragma unroll
            for (int s = 0; s < 8; ++s) acc[s] += xf * WcS[s * F_FEAT + L_ + lane];
        }
        #pragma unroll
        for (int s = 0; s < 8; ++s) {
            #pragma unroll
            for (int off = 32; off > 0; off >>= 1) acc[s] += __shfl_down(acc[s], off);
        }
        if (lane == 0) {
            float m = -1e30f;
            #pragma unroll
            for (int s = 0; s < 8; ++s) { acc[s] += bcS[s]; m = fmaxf(m, acc[s]); }
            float Z = 0.f; float e[8];
            #pragma unroll
            for (int s = 0; s < 8; ++s) { e[s] = expf(acc[s] - m); Z += e[s]; }
            float inv = 1.0f / Z;
            #pragma unroll
            for (int s = 0; s < 8; ++s) p_out[(size_t)bc * 8 + s] = e[s] * inv;
        }
    }
}

// ================= K4a: gather signal rows (bf16 -> bf16 copy) ===============
// row = bc*9 + k; k<8: window of leader channel; k=8: y_hat. Cols 336..351 = 0.
__global__ __launch_bounds__(256) void k_gather(const unsigned short* __restrict__ fullbf,
                                                const int* __restrict__ leader,
                                                const int* __restrict__ shiftp,
                                                unsigned short* __restrict__ sigbf) {
    int tid = threadIdx.x, w = tid >> 6, lane = tid & 63;
    int r0 = blockIdx.x * 16 + w * 4;
    for (int i = 0; i < 4; ++i) {
        int r = r0 + i;
        int bc = r / 9, k = r - bc * 9;
        int b = bc / C_;
        const unsigned short* src;
        if (k < 8) {
            int lead = leader[(size_t)bc * K_ + k];
            int sh = shiftp[(size_t)bc * K_ + k];
            src = fullbf + ((size_t)b * C_ + lead) * LHB_ + (L_ - sh);
        } else {
            src = fullbf + (size_t)bc * LHB_ + L_;
        }
        unsigned short* dst = sigbf + (size_t)r * 352;
        #pragma unroll
        for (int t = 0; t < 6; ++t) {
            int j = lane + t * 64;
            if (j < 352) dst[j] = (j < H_) ? src[j] : (unsigned short)0;
        }
    }
}

// ================= K4b: DFT as pure streaming MFMA GEMM =====================
__global__ __launch_bounds__(256) void k_dft2(const unsigned short* __restrict__ sigbf,
                                              const unsigned short* __restrict__ Tsw,
                                              unsigned short* __restrict__ Xbf) {
    int row0 = blockIdx.x * 64;
    int tid = threadIdx.x, w = tid >> 6, lane = tid & 63;
    const int NTB[5] = {0, 6, 12, 17, 22};
    int nt0 = NTB[w], ntn = NTB[w + 1] - nt0;
    int r15 = lane & 15, kg = lane >> 4;
    f32x4 acc[4][6];
    #pragma unroll
    for (int mf = 0; mf < 4; ++mf)
        #pragma unroll
        for (int j = 0; j < 6; ++j) acc[mf][j] = (f32x4){0.f, 0.f, 0.f, 0.f};
    for (int kc = 0; kc < 11; ++kc) {
        short8v a[4];
        #pragma unroll
        for (int mf = 0; mf < 4; ++mf)
            a[mf] = *(const short8v*)(sigbf + ((size_t)(row0 + mf * 16 + r15) * 352 + kc * 32 + kg * 8));
        #pragma unroll
        for (int j = 0; j < 6; ++j) {
            if (j >= ntn) continue;
            short8v bfr = *(const short8v*)(Tsw + ((size_t)(kc * 22 + nt0 + j) * 512 + lane * 8));
            #pragma unroll
            for (int mf = 0; mf < 4; ++mf)
                acc[mf][j] = __builtin_amdgcn_mfma_f32_16x16x32_bf16(a[mf], bfr, acc[mf][j], 0, 0, 0);
        }
    }
    #pragma unroll
    for (int mf = 0; mf < 4; ++mf)
        #pragma unroll
        for (int j = 0; j < 6; ++j) {
            if (j >= ntn) continue;
            int col = (nt0 + j) * 16 + r15;
            #pragma unroll
            for (int reg = 0; reg < 4; ++reg) {
                int row = row0 + mf * 16 + kg * 4 + reg;
                Xbf[(size_t)row * 352 + col] = f2bf(acc[mf][j][reg]);
            }
        }
}

// ================= K5: filter-combine X -> z (f-major, 8-bc register reuse) ==
__global__ __launch_bounds__(256) void k_z3(const unsigned* __restrict__ X32,
                                            const float* __restrict__ pbuf,
                                            const float4* __restrict__ stf4,
                                            const float2* __restrict__ stg3,
                                            unsigned short* __restrict__ zbf) {
    __shared__ float psL[ZNBC_][8];
    int tid = threadIdx.x;
    int bc0 = blockIdx.x * ZNBC_;
    if (tid < ZNBC_ * 8) {
        int bcl = tid >> 3, s = tid & 7;
        psL[bcl][s] = pbuf[(size_t)(bc0 + bcl) * 8 + s];
    }
    __syncthreads();

    if (tid < FREQ_) {
        int f = tid;
        float z1r[ZNBC_], z1i[ZNBC_], z2r[ZNBC_], z2i[ZNBC_], Yr[ZNBC_], Yi[ZNBC_];
        #pragma unroll
        for (int bcl = 0; bcl < ZNBC_; ++bcl) {
            z1r[bcl] = z1i[bcl] = z2r[bcl] = z2i[bcl] = 0.f;
            unsigned v = X32[((size_t)(bc0 + bcl) * 9 + 8) * 176 + f];
            Yr[bcl] = bf2f((unsigned short)(v & 0xffff));
            Yi[bcl] = bf2f((unsigned short)(v >> 16));
        }
        for (int k = 0; k < 8; ++k) {
            float4 stv[8];
            #pragma unroll
            for (int s = 0; s < 8; ++s) stv[s] = stf4[(size_t)(k * 8 + s) * FREQ_ + f];
            #pragma unroll
            for (int bcl = 0; bcl < ZNBC_; ++bcl) {
                float f1r = 0.f, f1i = 0.f, f2r = 0.f, f2i = 0.f;
                #pragma unroll
                for (int s = 0; s < 8; ++s) {
                    float p = psL[bcl][s];
                    f1r += p * stv[s].x; f1i += p * stv[s].y;
                    f2r += p * stv[s].z; f2i += p * stv[s].w;
                }
                unsigned v = X32[((size_t)(bc0 + bcl) * 9 + k) * 176 + f];
                float Xr = bf2f((unsigned short)(v & 0xffff));
                float Xi = bf2f((unsigned short)(v >> 16));
                float ar = Xr * f1r - Xi * f1i;
                float ai = Xr * f1i + Xi * f1r;
                z1r[bcl] += ar; z1i[bcl] += ai;
                float dr = ar - Yr[bcl], di = ai - Yi[bcl];
                z2r[bcl] += dr * f2r - di * f2i;
                z2i[bcl] += dr * f2i + di * f2r;
            }
        }
        #pragma unroll
        for (int bcl = 0; bcl < ZNBC_; ++bcl) {
            int bc = bc0 + bcl;
            float f3r = 0.f, f3i = 0.f;
            #pragma unroll
            for (int s = 0; s < 8; ++s) {
                float2 v3 = stg3[(size_t)s * FREQ_ + f];
                float p = psL[bcl][s];
                f3r += p * v3.x; f3i += p * v3.y;
            }
            unsigned short* zrow = zbf + (size_t)bc * 1024;
            zrow[f]       = f2bf(z1r[bcl]);  zrow[512 + f]       = f2bf(z1i[bcl]);
            zrow[169 + f] = f2bf(z2r[bcl]);  zrow[512 + 169 + f] = f2bf(z2i[bcl]);
            zrow[338 + f] = f2bf(Yr[bcl] * f3r - Yi[bcl] * f3i);
            zrow[512 + 338 + f] = f2bf(Yr[bcl] * f3i + Yi[bcl] * f3r);
        }
    } else if (tid >= 176 && tid < 176 + ZNBC_ * 10) {
        int t = tid - 176;
        int bcl = t / 10, o = t - bcl * 10;
        unsigned short* zrow = zbf + (size_t)(bc0 + bcl) * 1024;
        if (o < 5) zrow[507 + o] = 0;
        else       zrow[1019 + (o - 5)] = 0;
    }
}

// ================= K6: mixing + irfft fused (mixed stays in LDS) =============
__global__ __launch_bounds__(256) void k_mixir(const unsigned short* __restrict__ zbf,
                                               const unsigned short* __restrict__ W2sw,
                                               const float* __restrict__ bm_re,
                                               const float* __restrict__ bm_im,
                                               const unsigned short* __restrict__ Tir,
                                               const float* __restrict__ yhf,
                                               const float* __restrict__ muv,
                                               const float* __restrict__ nrm,
                                               float* __restrict__ ytmp) {
    __shared__ unsigned short Am[32 * 360];
    int bc0 = blockIdx.x * 32;
    int tid = threadIdx.x, w = tid >> 6, lane = tid & 63;
    int r15 = lane & 15, kg = lane >> 4;

    {
        const int NTB[5] = {0, 6, 12, 17, 22};
        int nt0 = NTB[w], ntn = NTB[w + 1] - nt0;
        f32x4 acc[2][6];
        #pragma unroll
        for (int mf = 0; mf < 2; ++mf)
            #pragma unroll
            for (int j = 0; j < 6; ++j) acc[mf][j] = (f32x4){0.f, 0.f, 0.f, 0.f};
        for (int kc = 0; kc < 32; ++kc) {
            short8v a[2];
            #pragma unroll
            for (int mf = 0; mf < 2; ++mf)
                a[mf] = *(const short8v*)(zbf + ((size_t)(bc0 + mf * 16 + r15) * 1024 + kc * 32 + kg * 8));
            #pragma unroll
            for (int j = 0; j < 6; ++j) {
                if (j >= ntn) continue;
                short8v bfr = *(const short8v*)(W2sw + ((size_t)(kc * 22 + nt0 + j) * 512 + lane * 8));
                #pragma unroll
                for (int mf = 0; mf < 2; ++mf)
                    acc[mf][j] = __builtin_amdgcn_mfma_f32_16x16x32_bf16(a[mf], bfr, acc[mf][j], 0, 0, 0);
            }
        }
        #pragma unroll
        for (int mf = 0; mf < 2; ++mf)
            #pragma unroll
            for (int j = 0; j < 6; ++j) {
                if (j >= ntn) continue;
                int col = (nt0 + j) * 16 + r15;
                #pragma unroll
                for (int reg = 0; reg < 4; ++reg) {
                    int row = mf * 16 + kg * 4 + reg;
                    float v = 0.f;
                    if (col < 2 * FREQ_) {
                        int g = col >> 1;
                        float bias = (col & 1) ? bm_im[g] : bm_re[g];
                        float wgt = (g == 0 || g == FREQ_ - 1) ? 1.0f : 2.0f;
                        v = (acc[mf][j][reg] + bias) * (wgt / (float)H_);
                    }
                    Am[row * 360 + col] = f2bf(v);
                }
            }
    }
    __syncthreads();

    {
        const int NTB[5] = {0, 6, 11, 16, 21};
        int nt0 = NTB[w], ntn = NTB[w + 1] - nt0;
        f32x4 acc[2][6];
        #pragma unroll
        for (int mf = 0; mf < 2; ++mf)
            #pragma unroll
            for (int j = 0; j < 6; ++j) acc[mf][j] = (f32x4){0.f, 0.f, 0.f, 0.f};
        for (int kc = 0; kc < 11; ++kc) {
            short8v a[2];
            #pragma unroll
            for (int mf = 0; mf < 2; ++mf)
                a[mf] = *(const short8v*)(Am + (size_t)(mf * 16 + r15) * 360 + kc * 32 + kg * 8);
            #pragma unroll
            for (int j = 0; j < 6; ++j) {
                if (j >= ntn) continue;
                short8v bfr = *(const short8v*)(Tir + ((size_t)(kc * 21 + nt0 + j) * 512 + lane * 8));
                #pragma unroll
                for (int mf = 0; mf < 2; ++mf)
                    acc[mf][j] = __builtin_amdgcn_mfma_f32_16x16x32_bf16(a[mf], bfr, acc[mf][j], 0, 0, 0);
            }
        }
        #pragma unroll
        for (int mf = 0; mf < 2; ++mf)
            #pragma unroll
            for (int j = 0; j < 6; ++j) {
                if (j >= ntn) continue;
                int h = (nt0 + j) * 16 + r15;
                #pragma unroll
                for (int reg = 0; reg < 4; ++reg) {
                    int bc = bc0 + mf * 16 + kg * 4 + reg;
                    float y = (yhf[(size_t)bc * H_ + h] + acc[mf][j][reg]) * nrm[bc] + muv[bc];
                    ytmp[(size_t)bc * H_ + h] = y;
                }
            }
    }
}

// ================= K8: transpose ytmp[b][c][h] -> out[b][h][c] ===============
__global__ __launch_bounds__(256) void k_out_t(const float* __restrict__ ytmp,
                                               float* __restrict__ out) {
    __shared__ float tile[32][33];
    int b = blockIdx.z;
    int h0 = blockIdx.x * 32, c0 = blockIdx.y * 32;
    int tx = threadIdx.x & 31, ty = threadIdx.x >> 5;
    #pragma unroll
    for (int i = 0; i < 4; ++i) {
        int cc = c0 + ty + i * 8, hh = h0 + tx;
        if (cc < C_ && hh < H_)
            tile[ty + i * 8][tx] = ytmp[((size_t)b * C_ + cc) * H_ + hh];
    }
    __syncthreads();
    #pragma unroll
    for (int i = 0; i < 4; ++i) {
        int hh = h0 + ty + i * 8, cc = c0 + tx;
        if (cc < C_ && hh < H_)
            out[((size_t)b * H_ + hh) * C_ + cc] = tile[tx][ty + i * 8];
    }
}

extern "C" void kernel_launch(void* const* d_in, const int* in_sizes, int n_in,
                              void* d_out, int out_size, void* d_ws, size_t ws_size,
                              hipStream_t stream) {
    const float* x     = (const float*)d_in[0];
    const float* r     = (const float*)d_in[1];
    const float* Wb    = (const float*)d_in[2];
    const float* bb    = (const float*)d_in[3];
    const float* Wc    = (const float*)d_in[4];
    const float* bcv   = (const float*)d_in[5];
    const float* st_re = (const float*)d_in[6];
    const float* st_im = (const float*)d_in[7];
    const float* Wm_re = (const float*)d_in[8];
    const float* Wm_im = (const float*)d_in[9];
    const float* bm_re = (const float*)d_in[10];
    const float* bm_im = (const float*)d_in[11];
    const int* leader  = (const int*)d_in[12];
    const int* shiftp  = (const int*)d_in[13];
    float* out = (float*)d_out;

    char* w = (char*)d_ws;
    auto carve = [&](size_t bytes) {
        char* p = w;
        w += (bytes + 255) & ~(size_t)255;
        return (void*)p;
    };
    unsigned short* Tdft = (unsigned short*)carve((size_t)11 * 22 * 512 * 2);
    unsigned short* Tir  = (unsigned short*)carve((size_t)11 * 21 * 512 * 2);
    unsigned short* W2   = (unsigned short*)carve((size_t)32 * 22 * 512 * 2);
    unsigned short* Wbsw = (unsigned short*)carve((size_t)16 * 21 * 512 * 2);
    float4*         stf4 = (float4*)carve((size_t)64 * FREQ_ * 16);
    float2*         stg3 = (float2*)carve((size_t)8 * FREQ_ * 8);
    float2*         part = (float2*)carve((size_t)B_ * 6 * 8 * 64 * 8);
    unsigned short* fullbf = (unsigned short*)carve((size_t)BCN_ * LHB_ * 2);
    float*          yhf  = (float*)carve((size_t)BCN_ * H_ * 4);
    float*          muv  = (float*)carve((size_t)BCN_ * 4);
    float*          nrm  = (float*)carve((size_t)BCN_ * 4);
    float*          pbuf = (float*)carve((size_t)BCN_ * 8 * 4);
    unsigned short* zbf  = (unsigned short*)carve((size_t)BCN_ * 1024 * 2);
    float*          ytmp = (float*)carve((size_t)BCN_ * H_ * 4);
    unsigned short* sigbf= (unsigned short*)carve((size_t)NROWP_ * 352 * 2);
    unsigned short* Xbf  = (unsigned short*)carve((size_t)NROWP_ * 352 * 2);

    hipLaunchKernelGGL(k_prep_dft, dim3(11 * 22), dim3(64), 0, stream, Tdft);
    hipLaunchKernelGGL(k_prep_ir,  dim3(11 * 21), dim3(64), 0, stream, Tir);
    hipLaunchKernelGGL(k_prep_w2,  dim3(32 * 22), dim3(64), 0, stream, Wm_re, Wm_im, W2);
    hipLaunchKernelGGL(k_prep_wb,  dim3(16 * 21), dim3(64), 0, stream, Wb, Wbsw);
    hipLaunchKernelGGL(k_prep_st2, dim3((64 * FREQ_ + 255) / 256), dim3(256), 0, stream,
                       st_re, st_im, stf4, stg3);
    hipLaunchKernelGGL(k_stats_part, dim3(6, 32, 8), dim3(256), 0, stream, x, part);
    hipLaunchKernelGGL(k_stats_fin, dim3(48), dim3(256), 0, stream, part, muv, nrm);
    hipLaunchKernelGGL(k_norm, dim3(6, 32, 8), dim3(256), 0, stream, x, muv, nrm, fullbf);
    hipLaunchKernelGGL(k_yhat, dim3(BCN_ / 32), dim3(256), 0, stream, fullbf, Wbsw, bb, fullbf, yhf);
    hipLaunchKernelGGL(k_p2, dim3(BCN_ / 16), dim3(256), 0, stream, fullbf, r, Wc, bcv, pbuf);
    hipLaunchKernelGGL(k_gather, dim3(NROW_ / 16), dim3(256), 0, stream,
                       fullbf, leader, shiftp, sigbf);
    hipLaunchKernelGGL(k_dft2, dim3(NROWP_ / 64), dim3(256), 0, stream, sigbf, Tdft, Xbf);
    hipLaunchKernelGGL(k_z3, dim3(BCN_ / ZNBC_), dim3(256), 0, stream,
                       (const unsigned*)Xbf, pbuf, stf4, stg3, zbf);
    hipLaunchKernelGGL(k_mixir, dim3(BCN_ / 32), dim3(256), 0, stream,
                       zbf, W2, bm_re, bm_im, Tir, yhf, muv, nrm, ytmp);
    hipLaunchKernelGGL(k_out_t, dim3((H_ + 31) / 32, (C_ + 31) / 32, B_), dim3(256), 0, stream,
                       ytmp, out);
}